// Round 13
// baseline (359.824 us; speedup 1.0000x reference)
//
#include <hip/hip_runtime.h>
#include <math.h>

#define NN 100000
#define EE 3200000
#define ET (EE + NN)
#define NG 64

// bucket sort params
#define NB 196         // ceil(NN/512) buckets
#define BWID 512       // nodes per bucket (dst >> 9)
#define PCHUNK 8192    // edges per partition block
#define PBLOCKS ((ET + PCHUNK - 1) / PCHUNK)

// xform1 split (merged-kernel halves), 128 nodes per 512-thread block
#define X1_SPLIT 50048
#define X1BLK_A 391    // ceil(50048/128)
#define X1BLK_B 391    // ceil((NN-X1_SPLIT)/128)

// workspace layout (4-byte units)
#define OFF_XL1B  0u           /* ushort[NN*32] = 1.6M floats */
#define OFF_XR1   1600000u     /* f32 3.2M -> ends 4.8M */
#define OFF_HL2B  8000000u     /* ushort[NN*64] = 3.2M floats -> 11.2M */
#define OFF_HR2   11200000u    /* f32 6.4M -> 17.6M */
#define OFF_BEDGE 8000000u     /* packed int[ET] = 3.3M, aliases HL2B head (dead before gather1x2) */
#define OFF_RP    17600000u    /* 100096 */
#define OFF_ESRC  17700096u    /* ET = 3.3M -> 21000096 */
#define OFF_POOL  21000096u    /* 4096 */
#define OFF_CNTG  21004192u    /* 64 */
#define OFF_BCNT  21004256u    /* 256 */
#define OFF_BOFF  21004512u    /* 256 */
#define OFF_GCUR  21004768u    /* 256 */
#define WS_UNITS  21005024u

__device__ __forceinline__ float lrelu(float v) { return fmaxf(v, 0.2f * v); }

__device__ __forceinline__ unsigned pack_bf2(float a, float b) {
  unsigned ua = __float_as_uint(a), ub = __float_as_uint(b);
  ua = (ua + 0x7FFFu + ((ua >> 16) & 1u)) >> 16;
  ub = (ub + 0x7FFFu + ((ub >> 16) & 1u)) & 0xFFFF0000u;
  return ua | ub;
}
__device__ __forceinline__ float bf_lo(unsigned u) { return __uint_as_float(u << 16); }
__device__ __forceinline__ float bf_hi(unsigned u) { return __uint_as_float(u & 0xFFFF0000u); }

// ======================= small CSR kernels =======================
__global__ __launch_bounds__(256) void k_bcount(const int* __restrict__ ei,
                                                int* __restrict__ bcnt) {
  __shared__ int h[NB];
  for (int i = threadIdx.x; i < NB; i += 256) h[i] = 0;
  __syncthreads();
  for (long e = (long)blockIdx.x * 256 + threadIdx.x; e < ET; e += (long)gridDim.x * 256) {
    int d = (e < EE) ? ei[EE + e] : (int)(e - EE);
    atomicAdd(&h[d >> 9], 1);
  }
  __syncthreads();
  for (int i = threadIdx.x; i < NB; i += 256) if (h[i]) atomicAdd(&bcnt[i], h[i]);
}

__global__ __launch_bounds__(256) void k_bscan(const int* __restrict__ bcnt,
                                               int* __restrict__ boff, int* __restrict__ gcur) {
  __shared__ int sd[256];
  int t = threadIdx.x;
  int v = (t < NB) ? bcnt[t] : 0;
  sd[t] = v;
  __syncthreads();
  for (int o = 1; o < 256; o <<= 1) {
    int u = (t >= o) ? sd[t - o] : 0;
    __syncthreads();
    sd[t] += u;
    __syncthreads();
  }
  if (t < NB) { boff[t] = sd[t] - v; gcur[t] = sd[t] - v; }
  if (t == 0) boff[NB] = ET;
}

// ======================= device roles for merged kernels =======================
__device__ void part_role(char* smem, const int* __restrict__ ei,
                          int* __restrict__ gcur, int* __restrict__ bedge, int pblk) {
  int* cnt   = (int*)smem;
  int* lbase = cnt + NB;
  int* gbase = lbase + NB;
  int* sc    = gbase + NB;
  int* buf   = sc + 256;
  unsigned char* bkt = (unsigned char*)(buf + PCHUNK);
  int tid = threadIdx.x;
  long e0 = (long)pblk * PCHUNK;
  int nedge = (e0 + PCHUNK <= ET) ? PCHUNK : (int)(ET - e0);

  for (int i = tid; i < NB; i += 512) cnt[i] = 0;
  __syncthreads();
  for (int i = tid; i < nedge; i += 512) {
    long e = e0 + i;
    int d = (e < EE) ? ei[EE + e] : (int)(e - EE);
    atomicAdd(&cnt[d >> 9], 1);
  }
  __syncthreads();
  if (tid < 256) sc[tid] = (tid < NB) ? cnt[tid] : 0;
  __syncthreads();
  for (int o = 1; o < 256; o <<= 1) {
    int u = (tid < 256 && tid >= o) ? sc[tid - o] : 0;
    __syncthreads();
    if (tid < 256) sc[tid] += u;
    __syncthreads();
  }
  if (tid < NB) lbase[tid] = sc[tid] - cnt[tid];
  __syncthreads();
  if (tid < NB) {
    int c = cnt[tid];
    gbase[tid] = c ? atomicAdd(&gcur[tid], c) : 0;
    cnt[tid] = 0;
  }
  __syncthreads();
  for (int i = tid; i < nedge; i += 512) {
    long e = e0 + i;
    int s, d;
    if (e < EE) { s = ei[e]; d = ei[EE + e]; }
    else { s = (int)(e - EE); d = s; }
    int b = d >> 9;
    int r = atomicAdd(&cnt[b], 1);
    int idx = lbase[b] + r;
    buf[idx] = s | ((d & 511) << 17);
    bkt[idx] = (unsigned char)b;
  }
  __syncthreads();
  for (int i = tid; i < nedge; i += 512) {
    int p = buf[i];
    int b = bkt[i];
    bedge[gbase[b] + (i - lbase[b])] = p;
  }
}

__device__ void csr_role(char* smem, const int* __restrict__ boff,
                         const int* __restrict__ bedge,
                         int* __restrict__ rp, int* __restrict__ esrc, int b) {
  int* sdeg  = (int*)smem;
  int* sscan = sdeg + BWID;
  int t = threadIdx.x;
  int n0 = b * BWID;
  int lo = boff[b], hi = boff[b + 1];
  sdeg[t] = 0;
  __syncthreads();
  for (int i = lo + t; i < hi; i += 512) {
    int p = bedge[i];
    atomicAdd(&sdeg[p >> 17], 1);
  }
  __syncthreads();
  int v = sdeg[t];
  sscan[t] = v;
  __syncthreads();
  for (int o = 1; o < 512; o <<= 1) {
    int u = (t >= o) ? sscan[t - o] : 0;
    __syncthreads();
    sscan[t] += u;
    __syncthreads();
  }
  int excl = sscan[t] - v;
  int n = n0 + t;
  if (n < NN) rp[n] = lo + excl;
  if (b == NB - 1 && t == 0) rp[NN] = ET;
  __syncthreads();
  sdeg[t] = lo + excl;   // reuse as cursor
  __syncthreads();
  for (int i = lo + t; i < hi; i += 512) {
    int p = bedge[i];
    int pos = atomicAdd(&sdeg[p >> 17], 1);
    esrc[pos] = p & 0x1FFFF;
  }
}

// xform1 role (512 threads, 128 nodes/block): 4-node blocking, 16KB W-quarters
#define FMA4A(a, xv) \
  a.x += xv.x*w0.x + xv.y*w1.x + xv.z*w2.x + xv.w*w3.x; \
  a.y += xv.x*w0.y + xv.y*w1.y + xv.z*w2.y + xv.w*w3.y; \
  a.z += xv.x*w0.z + xv.y*w1.z + xv.z*w2.z + xv.w*w3.z; \
  a.w += xv.x*w0.w + xv.y*w1.w + xv.z*w2.w + xv.w*w3.w;

__device__ void xform1_role(char* smem, const float* __restrict__ x,
                            const float* __restrict__ Wl, const float* __restrict__ bl,
                            const float* __restrict__ Wr, const float* __restrict__ br,
                            unsigned short* __restrict__ xl1b, float* __restrict__ xr1,
                            int n_base) {
  float* Wlds = (float*)smem;   // 64*64 floats = 16 KB per quarter
  int tid = threadIdx.x;
  int ci = tid & 15;
  int cbase = ci * 4;
  int n0 = n_base + (tid >> 4) * 4;
  int r0 = n0 + 0 < NN ? n0 + 0 : NN - 1;
  int r1 = n0 + 1 < NN ? n0 + 1 : NN - 1;
  int r2 = n0 + 2 < NN ? n0 + 2 : NN - 1;
  int r3 = n0 + 3 < NN ? n0 + 3 : NN - 1;
  const float* xb0 = x + (size_t)r0 * 256;
  const float* xb1 = x + (size_t)r1 * 256;
  const float* xb2 = x + (size_t)r2 * 256;
  const float* xb3 = x + (size_t)r3 * 256;
  float4 acc0 = {0,0,0,0}, acc1 = {0,0,0,0}, acc2 = {0,0,0,0}, acc3 = {0,0,0,0};

  for (int q = 0; q < 4; ++q) {
    int k0 = q * 64;
    __syncthreads();
    for (int i = tid; i < 64 * 64; i += 512) {
      int k = (i >> 6) + k0, c = i & 63;
      Wlds[i] = (c < 32) ? Wl[k * 32 + c] : Wr[k * 32 + (c - 32)];
    }
    __syncthreads();
#pragma unroll 2
    for (int kk = 0; kk < 64; kk += 4) {
      int k = k0 + kk;
      float4 xv0 = *(const float4*)(xb0 + k);
      float4 xv1 = *(const float4*)(xb1 + k);
      float4 xv2 = *(const float4*)(xb2 + k);
      float4 xv3 = *(const float4*)(xb3 + k);
      const float* wr = &Wlds[kk * 64 + cbase];
      float4 w0 = *(const float4*)(wr);
      float4 w1 = *(const float4*)(wr + 64);
      float4 w2 = *(const float4*)(wr + 128);
      float4 w3 = *(const float4*)(wr + 192);
      FMA4A(acc0, xv0)
      FMA4A(acc1, xv1)
      FMA4A(acc2, xv2)
      FMA4A(acc3, xv3)
    }
  }
  float4 acc[4] = {acc0, acc1, acc2, acc3};
  if (cbase < 32) {
    float4 bv = { bl[cbase], bl[cbase+1], bl[cbase+2], bl[cbase+3] };
#pragma unroll
    for (int j = 0; j < 4; ++j) {
      int n = n0 + j;
      if (n < NN) {
        uint2 o = { pack_bf2(acc[j].x + bv.x, acc[j].y + bv.y),
                    pack_bf2(acc[j].z + bv.z, acc[j].w + bv.w) };
        *(uint2*)(xl1b + (size_t)n * 32 + cbase) = o;
      }
    }
  } else {
    int c2 = cbase - 32;
    float4 bv = { br[c2], br[c2+1], br[c2+2], br[c2+3] };
#pragma unroll
    for (int j = 0; j < 4; ++j) {
      int n = n0 + j;
      if (n < NN) {
        float4 o = { acc[j].x + bv.x, acc[j].y + bv.y, acc[j].z + bv.z, acc[j].w + bv.w };
        *(float4*)(xr1 + (size_t)n * 32 + c2) = o;
      }
    }
  }
}

// ======================= merged kernels (role by blockIdx) =======================
__global__ __launch_bounds__(512) void k_part_x1(
    const int* __restrict__ ei, int* __restrict__ gcur, int* __restrict__ bedge,
    const float* __restrict__ x,
    const float* __restrict__ Wl, const float* __restrict__ bl,
    const float* __restrict__ Wr, const float* __restrict__ br,
    unsigned short* __restrict__ xl1b, float* __restrict__ xr1) {
  extern __shared__ char smem[];
  if (blockIdx.x < PBLOCKS)
    part_role(smem, ei, gcur, bedge, blockIdx.x);
  else
    xform1_role(smem, x, Wl, bl, Wr, br, xl1b, xr1, (blockIdx.x - PBLOCKS) * 128);
}

__global__ __launch_bounds__(512) void k_csr_x1(
    const int* __restrict__ boff, const int* __restrict__ bedge,
    int* __restrict__ rp, int* __restrict__ esrc,
    const float* __restrict__ x,
    const float* __restrict__ Wl, const float* __restrict__ bl,
    const float* __restrict__ Wr, const float* __restrict__ br,
    unsigned short* __restrict__ xl1b, float* __restrict__ xr1) {
  extern __shared__ char smem[];
  if (blockIdx.x < NB)
    csr_role(smem, boff, bedge, rp, esrc, blockIdx.x);
  else
    xform1_role(smem, x, Wl, bl, Wr, br, xl1b, xr1,
                X1_SPLIT + (blockIdx.x - NB) * 128);
}

// ======================= fused layer-1 gather + layer-2 transform =======================
// gather phase: 32 lanes/node, 8 nodes/block, unroll x4 -> h in LDS;
// xform phase: thread (ni,ci) computes node ni, cols ci*4..+3 of 128 from LDS W2.
__global__ __launch_bounds__(256) void k_gather1x2(
    const int* __restrict__ rp, const int* __restrict__ esrc,
    const unsigned short* __restrict__ xl1b, const float* __restrict__ xr1,
    const float* __restrict__ att1, const float* __restrict__ bias1,
    const float* __restrict__ W2l, const float* __restrict__ b2l,
    const float* __restrict__ W2r, const float* __restrict__ b2r,
    unsigned short* __restrict__ hl2b, float* __restrict__ hr2) {
  __shared__ float W2lds[32 * 128];   // 16 KB
  __shared__ float hlds[8][33];       // +1 pad
  int tid = threadIdx.x;
  for (int i = tid; i < 32 * 128; i += 256) {
    int k = i >> 7, c = i & 127;
    W2lds[i] = (c < 64) ? W2l[k * 64 + c] : W2r[k * 64 + (c - 64)];
  }
  int n = blockIdx.x * 8 + (tid >> 5);   // NN % 8 == 0, grid exact
  int l = tid & 31;
  float av = att1[l];
  float xr = xr1[(size_t)n * 32 + l];
  int rpn = rp[n], dg = rp[n + 1] - rpn;
  float acc = 0.0f, den = 0.0f;
  int j = 0;
  for (; j + 4 <= dg; j += 4) {
    int s0 = esrc[rpn + j + 0];
    int s1 = esrc[rpn + j + 1];
    int s2 = esrc[rpn + j + 2];
    int s3 = esrc[rpn + j + 3];
    float x0 = bf_lo(xl1b[(size_t)s0 * 32 + l]);
    float x1 = bf_lo(xl1b[(size_t)s1 * 32 + l]);
    float x2 = bf_lo(xl1b[(size_t)s2 * 32 + l]);
    float x3 = bf_lo(xl1b[(size_t)s3 * 32 + l]);
    float p0 = lrelu(x0 + xr) * av;
    float p1 = lrelu(x1 + xr) * av;
    float p2 = lrelu(x2 + xr) * av;
    float p3 = lrelu(x3 + xr) * av;
    p0 += __shfl_xor(p0, 1); p1 += __shfl_xor(p1, 1);
    p2 += __shfl_xor(p2, 1); p3 += __shfl_xor(p3, 1);
    p0 += __shfl_xor(p0, 2); p1 += __shfl_xor(p1, 2);
    p2 += __shfl_xor(p2, 2); p3 += __shfl_xor(p3, 2);
    float w0 = __expf(p0), w1 = __expf(p1), w2 = __expf(p2), w3 = __expf(p3);
    den += w0 + w1 + w2 + w3;
    acc += w0 * x0 + w1 * x1 + w2 * x2 + w3 * x3;
  }
  for (; j < dg; ++j) {
    int s = esrc[rpn + j];
    float xl = bf_lo(xl1b[(size_t)s * 32 + l]);
    float p = lrelu(xl + xr) * av;
    p += __shfl_xor(p, 1);
    p += __shfl_xor(p, 2);
    float w = __expf(p);
    den += w;
    acc += w * xl;
  }
  float v = acc / (den + 1e-16f) + bias1[l];
  v = v > 0.0f ? v : expm1f(v);
  hlds[tid >> 5][l] = v;
  __syncthreads();

  // layer-2 transform from LDS
  int ni = tid >> 5, ci = tid & 31, cbase = ci * 4;
  float4 a = {0,0,0,0};
#pragma unroll
  for (int k = 0; k < 32; ++k) {
    float hv = hlds[ni][k];
    float4 wv = *(const float4*)(&W2lds[k * 128 + cbase]);
    a.x += hv * wv.x; a.y += hv * wv.y; a.z += hv * wv.z; a.w += hv * wv.w;
  }
  int no = blockIdx.x * 8 + ni;
  if (cbase < 64) {
    uint2 o = { pack_bf2(a.x + b2l[cbase], a.y + b2l[cbase + 1]),
                pack_bf2(a.z + b2l[cbase + 2], a.w + b2l[cbase + 3]) };
    *(uint2*)(hl2b + (size_t)no * 64 + cbase) = o;
  } else {
    int c2 = cbase - 64;
    float4 o = { a.x + b2r[c2], a.y + b2r[c2 + 1], a.z + b2r[c2 + 2], a.w + b2r[c2 + 3] };
    *(float4*)(hr2 + (size_t)no * 64 + c2) = o;
  }
}

// ======================= layer-2 gather (bf16 hl) + fused pooling, unroll x8 ==========
#define G2_P(qq, pp) { \
  float4 U0 = { bf_lo(qq.x), bf_hi(qq.x), bf_lo(qq.y), bf_hi(qq.y) }; \
  float4 U1 = { bf_lo(qq.z), bf_hi(qq.z), bf_lo(qq.w), bf_hi(qq.w) }; \
  pp = lrelu(U0.x + hr0.x) * ac0.x + lrelu(U0.y + hr0.y) * ac0.y \
     + lrelu(U0.z + hr0.z) * ac0.z + lrelu(U0.w + hr0.w) * ac0.w \
     + lrelu(U1.x + hr1.x) * ac1.x + lrelu(U1.y + hr1.y) * ac1.y \
     + lrelu(U1.z + hr1.z) * ac1.z + lrelu(U1.w + hr1.w) * ac1.w; }

#define G2_ACC(qq, ww) { \
  float4 U0 = { bf_lo(qq.x), bf_hi(qq.x), bf_lo(qq.y), bf_hi(qq.y) }; \
  float4 U1 = { bf_lo(qq.z), bf_hi(qq.z), bf_lo(qq.w), bf_hi(qq.w) }; \
  a0.x += ww * U0.x; a0.y += ww * U0.y; a0.z += ww * U0.z; a0.w += ww * U0.w; \
  a1.x += ww * U1.x; a1.y += ww * U1.y; a1.z += ww * U1.z; a1.w += ww * U1.w; }

__global__ __launch_bounds__(256) void k_gather2(
    const int* __restrict__ rp, const int* __restrict__ esrc,
    const unsigned short* __restrict__ hl2b, const float* __restrict__ hr2,
    const float* __restrict__ att2, const float* __restrict__ bias2,
    const int* __restrict__ batch,
    float* __restrict__ pool, float* __restrict__ cntg) {
  __shared__ float ssum[4][64];
  __shared__ float scnt[4];
  int tid = threadIdx.x;
  int n = (blockIdx.x * 256 + tid) >> 3;
  int l8 = tid & 7;
  int nblk0 = blockIdx.x * 32;
  int gmin = batch[nblk0];
  int gspan = batch[nblk0 + 31] - gmin + 1;   // <=4 (min graph size >> 32)
  ssum[tid >> 6][tid & 63] = 0.0f;
  if (tid < 4) scnt[tid] = 0.0f;
  __syncthreads();

  float4 ac0 = *(const float4*)(att2 + l8 * 8);
  float4 ac1 = *(const float4*)(att2 + l8 * 8 + 4);
  float4 bs0 = *(const float4*)(bias2 + l8 * 8);
  float4 bs1 = *(const float4*)(bias2 + l8 * 8 + 4);
  const float4* hrp = (const float4*)(hr2 + (size_t)n * 64 + l8 * 8);
  float4 hr0 = hrp[0], hr1 = hrp[1];
  int rpn = rp[n], dg = rp[n + 1] - rpn;
  float4 a0 = {0,0,0,0}, a1 = {0,0,0,0};
  float den = 0.0f;
  int j = 0;
  for (; j + 8 <= dg; j += 8) {
    int s[8];
#pragma unroll
    for (int t = 0; t < 8; ++t) s[t] = esrc[rpn + j + t];
    uint4 q[8];
#pragma unroll
    for (int t = 0; t < 8; ++t) q[t] = *(const uint4*)(hl2b + (size_t)s[t] * 64 + l8 * 8);
    float p[8];
#pragma unroll
    for (int t = 0; t < 8; ++t) { G2_P(q[t], p[t]) }
#pragma unroll
    for (int t = 0; t < 8; ++t) {
      p[t] += __shfl_xor(p[t], 1);
      p[t] += __shfl_xor(p[t], 2);
      p[t] += __shfl_xor(p[t], 4);
    }
#pragma unroll
    for (int t = 0; t < 8; ++t) {
      float w = __expf(p[t]);
      den += w;
      G2_ACC(q[t], w)
    }
  }
  for (; j < dg; ++j) {
    int s = esrc[rpn + j];
    uint4 q0 = *(const uint4*)(hl2b + (size_t)s * 64 + l8 * 8);
    float p;
    G2_P(q0, p)
    p += __shfl_xor(p, 1);
    p += __shfl_xor(p, 2);
    p += __shfl_xor(p, 4);
    float w = __expf(p);
    den += w;
    G2_ACC(q0, w)
  }
  float inv = 1.0f / (den + 1e-16f);
  int gi = batch[n] - gmin;
  float* sp = &ssum[gi][l8 * 8];
  atomicAdd(sp + 0, a0.x * inv + bs0.x);
  atomicAdd(sp + 1, a0.y * inv + bs0.y);
  atomicAdd(sp + 2, a0.z * inv + bs0.z);
  atomicAdd(sp + 3, a0.w * inv + bs0.w);
  atomicAdd(sp + 4, a1.x * inv + bs1.x);
  atomicAdd(sp + 5, a1.y * inv + bs1.y);
  atomicAdd(sp + 6, a1.z * inv + bs1.z);
  atomicAdd(sp + 7, a1.w * inv + bs1.w);
  if (l8 == 0) atomicAdd(&scnt[gi], 1.0f);
  __syncthreads();
  for (int i = tid; i < gspan * 64; i += 256)
    atomicAdd(pool + (size_t)(gmin + (i >> 6)) * 64 + (i & 63), ssum[i >> 6][i & 63]);
  if (tid < gspan) atomicAdd(cntg + gmin + tid, scnt[tid]);
}

__global__ __launch_bounds__(256) void k_final(
    const float* __restrict__ pool, const float* __restrict__ cntg,
    float* __restrict__ out) {
  int i = blockIdx.x * 256 + threadIdx.x;
  if (i < NG * 64) out[i] = pool[i] / fmaxf(cntg[i >> 6], 1.0f);
}

extern "C" void kernel_launch(void* const* d_in, const int* in_sizes, int n_in,
                              void* d_out, int out_size, void* d_ws, size_t ws_size,
                              hipStream_t stream) {
  const float* x     = (const float*)d_in[0];
  const int*   ei    = (const int*)d_in[1];
  const int*   batch = (const int*)d_in[2];
  const float* W1l   = (const float*)d_in[3];
  const float* b1l   = (const float*)d_in[4];
  const float* W1r   = (const float*)d_in[5];
  const float* b1r   = (const float*)d_in[6];
  const float* att1  = (const float*)d_in[7];
  const float* bias1 = (const float*)d_in[8];
  const float* W2l   = (const float*)d_in[9];
  const float* b2l   = (const float*)d_in[10];
  const float* W2r   = (const float*)d_in[11];
  const float* b2r   = (const float*)d_in[12];
  const float* att2  = (const float*)d_in[13];
  const float* bias2 = (const float*)d_in[14];
  float* ws = (float*)d_ws;
  int*   wi = (int*)d_ws;
  float* out = (float*)d_out;

  // zero pool + cntg + bcnt (contiguous region)
  hipMemsetAsync(ws + OFF_POOL, 0, (size_t)(WS_UNITS - OFF_POOL) * 4, stream);

  // CSR build; xform1 halves ride along in the part/csr launches (independent work)
  k_bcount<<<512, 256, 0, stream>>>(ei, wi + OFF_BCNT);
  k_bscan<<<1, 256, 0, stream>>>(wi + OFF_BCNT, wi + OFF_BOFF, wi + OFF_GCUR);
  k_part_x1<<<PBLOCKS + X1BLK_A, 512, 44352, stream>>>(
      ei, wi + OFF_GCUR, wi + OFF_BEDGE,
      x, W1l, b1l, W1r, b1r, (unsigned short*)(ws + OFF_XL1B), ws + OFF_XR1);
  k_csr_x1<<<NB + X1BLK_B, 512, 16384, stream>>>(
      wi + OFF_BOFF, wi + OFF_BEDGE, wi + OFF_RP, wi + OFF_ESRC,
      x, W1l, b1l, W1r, b1r, (unsigned short*)(ws + OFF_XL1B), ws + OFF_XR1);

  // fused layer-1 gather + layer-2 transform (writes hl2b over dead bedge region)
  k_gather1x2<<<NN / 8, 256, 0, stream>>>(wi + OFF_RP, wi + OFF_ESRC,
                                          (const unsigned short*)(ws + OFF_XL1B), ws + OFF_XR1,
                                          att1, bias1, W2l, b2l, W2r, b2r,
                                          (unsigned short*)(ws + OFF_HL2B), ws + OFF_HR2);
  k_gather2<<<(NN * 8 + 255) / 256, 256, 0, stream>>>(wi + OFF_RP, wi + OFF_ESRC,
                                                      (const unsigned short*)(ws + OFF_HL2B),
                                                      ws + OFF_HR2, att2, bias2, batch,
                                                      ws + OFF_POOL, ws + OFF_CNTG);
  k_final<<<16, 256, 0, stream>>>(ws + OFF_POOL, ws + OFF_CNTG, out);
}

// Round 14
// 352.419 us; speedup vs baseline: 1.0210x; 1.0210x over previous
//
#include <hip/hip_runtime.h>
#include <math.h>

#define NN 100000
#define EE 3200000
#define ET (EE + NN)
#define NG 64

// bucket sort params
#define NB 196         // ceil(NN/512) buckets
#define BWID 512       // nodes per bucket (dst >> 9)
#define PCHUNK 8192    // edges per partition block
#define PBLOCKS ((ET + PCHUNK - 1) / PCHUNK)

// xform1 split (merged-kernel halves), 128 nodes per 512-thread block
#define X1_SPLIT 50048
#define X1BLK_A 391    // ceil(50048/128)
#define X1BLK_B 391    // ceil((NN-X1_SPLIT)/128)

// workspace layout (4-byte units)
#define OFF_XL1B  0u           /* ushort[NN*32] = 1.6M floats */
#define OFF_XR1   1600000u     /* f32 3.2M -> ends 4.8M */
#define OFF_HL2B  8000000u     /* ushort[NN*64] = 3.2M floats -> 11.2M */
#define OFF_HR2   11200000u    /* f32 6.4M -> 17.6M */
#define OFF_BEDGE 8000000u     /* packed int[ET] = 3.3M, aliases HL2B head (dead before gather1x2) */
#define OFF_RP    17600000u    /* 100096 */
#define OFF_ESRC  17700096u    /* ET = 3.3M -> 21000096 */
#define OFF_POOL  21000096u    /* 4096 */
#define OFF_CNTG  21004192u    /* 64 */
#define OFF_BCNT  21004256u    /* 256 */
#define OFF_BOFF  21004512u    /* 256 */
#define OFF_GCUR  21004768u    /* 256 */
#define OFF_AL2   21005024u    /* f32[NN] */
#define OFF_AR2   21105024u    /* f32[NN] */
#define WS_UNITS  21205024u

__device__ __forceinline__ float lrelu(float v) { return fmaxf(v, 0.2f * v); }

__device__ __forceinline__ unsigned pack_bf2(float a, float b) {
  unsigned ua = __float_as_uint(a), ub = __float_as_uint(b);
  ua = (ua + 0x7FFFu + ((ua >> 16) & 1u)) >> 16;
  ub = (ub + 0x7FFFu + ((ub >> 16) & 1u)) & 0xFFFF0000u;
  return ua | ub;
}
__device__ __forceinline__ float bf_lo(unsigned u) { return __uint_as_float(u << 16); }
__device__ __forceinline__ float bf_hi(unsigned u) { return __uint_as_float(u & 0xFFFF0000u); }

// ======================= small CSR kernels =======================
__global__ __launch_bounds__(256) void k_bcount(const int* __restrict__ ei,
                                                int* __restrict__ bcnt) {
  __shared__ int h[NB];
  for (int i = threadIdx.x; i < NB; i += 256) h[i] = 0;
  __syncthreads();
  for (long e = (long)blockIdx.x * 256 + threadIdx.x; e < ET; e += (long)gridDim.x * 256) {
    int d = (e < EE) ? ei[EE + e] : (int)(e - EE);
    atomicAdd(&h[d >> 9], 1);
  }
  __syncthreads();
  for (int i = threadIdx.x; i < NB; i += 256) if (h[i]) atomicAdd(&bcnt[i], h[i]);
}

__global__ __launch_bounds__(256) void k_bscan(const int* __restrict__ bcnt,
                                               int* __restrict__ boff, int* __restrict__ gcur) {
  __shared__ int sd[256];
  int t = threadIdx.x;
  int v = (t < NB) ? bcnt[t] : 0;
  sd[t] = v;
  __syncthreads();
  for (int o = 1; o < 256; o <<= 1) {
    int u = (t >= o) ? sd[t - o] : 0;
    __syncthreads();
    sd[t] += u;
    __syncthreads();
  }
  if (t < NB) { boff[t] = sd[t] - v; gcur[t] = sd[t] - v; }
  if (t == 0) boff[NB] = ET;
}

// ======================= device roles for merged kernels =======================
__device__ void part_role(char* smem, const int* __restrict__ ei,
                          int* __restrict__ gcur, int* __restrict__ bedge, int pblk) {
  int* cnt   = (int*)smem;
  int* lbase = cnt + NB;
  int* gbase = lbase + NB;
  int* sc    = gbase + NB;
  int* buf   = sc + 256;
  unsigned char* bkt = (unsigned char*)(buf + PCHUNK);
  int tid = threadIdx.x;
  long e0 = (long)pblk * PCHUNK;
  int nedge = (e0 + PCHUNK <= ET) ? PCHUNK : (int)(ET - e0);

  for (int i = tid; i < NB; i += 512) cnt[i] = 0;
  __syncthreads();
  for (int i = tid; i < nedge; i += 512) {
    long e = e0 + i;
    int d = (e < EE) ? ei[EE + e] : (int)(e - EE);
    atomicAdd(&cnt[d >> 9], 1);
  }
  __syncthreads();
  if (tid < 256) sc[tid] = (tid < NB) ? cnt[tid] : 0;
  __syncthreads();
  for (int o = 1; o < 256; o <<= 1) {
    int u = (tid < 256 && tid >= o) ? sc[tid - o] : 0;
    __syncthreads();
    if (tid < 256) sc[tid] += u;
    __syncthreads();
  }
  if (tid < NB) lbase[tid] = sc[tid] - cnt[tid];
  __syncthreads();
  if (tid < NB) {
    int c = cnt[tid];
    gbase[tid] = c ? atomicAdd(&gcur[tid], c) : 0;
    cnt[tid] = 0;
  }
  __syncthreads();
  for (int i = tid; i < nedge; i += 512) {
    long e = e0 + i;
    int s, d;
    if (e < EE) { s = ei[e]; d = ei[EE + e]; }
    else { s = (int)(e - EE); d = s; }
    int b = d >> 9;
    int r = atomicAdd(&cnt[b], 1);
    int idx = lbase[b] + r;
    buf[idx] = s | ((d & 511) << 17);
    bkt[idx] = (unsigned char)b;
  }
  __syncthreads();
  for (int i = tid; i < nedge; i += 512) {
    int p = buf[i];
    int b = bkt[i];
    bedge[gbase[b] + (i - lbase[b])] = p;
  }
}

__device__ void csr_role(char* smem, const int* __restrict__ boff,
                         const int* __restrict__ bedge,
                         int* __restrict__ rp, int* __restrict__ esrc, int b) {
  int* sdeg  = (int*)smem;
  int* sscan = sdeg + BWID;
  int t = threadIdx.x;
  int n0 = b * BWID;
  int lo = boff[b], hi = boff[b + 1];
  sdeg[t] = 0;
  __syncthreads();
  for (int i = lo + t; i < hi; i += 512) {
    int p = bedge[i];
    atomicAdd(&sdeg[p >> 17], 1);
  }
  __syncthreads();
  int v = sdeg[t];
  sscan[t] = v;
  __syncthreads();
  for (int o = 1; o < 512; o <<= 1) {
    int u = (t >= o) ? sscan[t - o] : 0;
    __syncthreads();
    sscan[t] += u;
    __syncthreads();
  }
  int excl = sscan[t] - v;
  int n = n0 + t;
  if (n < NN) rp[n] = lo + excl;
  if (b == NB - 1 && t == 0) rp[NN] = ET;
  __syncthreads();
  sdeg[t] = lo + excl;   // reuse as cursor
  __syncthreads();
  for (int i = lo + t; i < hi; i += 512) {
    int p = bedge[i];
    int pos = atomicAdd(&sdeg[p >> 17], 1);
    esrc[pos] = p & 0x1FFFF;
  }
}

// xform1 role (512 threads, 128 nodes/block): 4-node blocking, 16KB W-quarters
#define FMA4A(a, xv) \
  a.x += xv.x*w0.x + xv.y*w1.x + xv.z*w2.x + xv.w*w3.x; \
  a.y += xv.x*w0.y + xv.y*w1.y + xv.z*w2.y + xv.w*w3.y; \
  a.z += xv.x*w0.z + xv.y*w1.z + xv.z*w2.z + xv.w*w3.z; \
  a.w += xv.x*w0.w + xv.y*w1.w + xv.z*w2.w + xv.w*w3.w;

__device__ void xform1_role(char* smem, const float* __restrict__ x,
                            const float* __restrict__ Wl, const float* __restrict__ bl,
                            const float* __restrict__ Wr, const float* __restrict__ br,
                            unsigned short* __restrict__ xl1b, float* __restrict__ xr1,
                            int n_base) {
  float* Wlds = (float*)smem;   // 64*64 floats = 16 KB per quarter
  int tid = threadIdx.x;
  int ci = tid & 15;
  int cbase = ci * 4;
  int n0 = n_base + (tid >> 4) * 4;
  int r0 = n0 + 0 < NN ? n0 + 0 : NN - 1;
  int r1 = n0 + 1 < NN ? n0 + 1 : NN - 1;
  int r2 = n0 + 2 < NN ? n0 + 2 : NN - 1;
  int r3 = n0 + 3 < NN ? n0 + 3 : NN - 1;
  const float* xb0 = x + (size_t)r0 * 256;
  const float* xb1 = x + (size_t)r1 * 256;
  const float* xb2 = x + (size_t)r2 * 256;
  const float* xb3 = x + (size_t)r3 * 256;
  float4 acc0 = {0,0,0,0}, acc1 = {0,0,0,0}, acc2 = {0,0,0,0}, acc3 = {0,0,0,0};

  for (int q = 0; q < 4; ++q) {
    int k0 = q * 64;
    __syncthreads();
    for (int i = tid; i < 64 * 64; i += 512) {
      int k = (i >> 6) + k0, c = i & 63;
      Wlds[i] = (c < 32) ? Wl[k * 32 + c] : Wr[k * 32 + (c - 32)];
    }
    __syncthreads();
#pragma unroll 2
    for (int kk = 0; kk < 64; kk += 4) {
      int k = k0 + kk;
      float4 xv0 = *(const float4*)(xb0 + k);
      float4 xv1 = *(const float4*)(xb1 + k);
      float4 xv2 = *(const float4*)(xb2 + k);
      float4 xv3 = *(const float4*)(xb3 + k);
      const float* wr = &Wlds[kk * 64 + cbase];
      float4 w0 = *(const float4*)(wr);
      float4 w1 = *(const float4*)(wr + 64);
      float4 w2 = *(const float4*)(wr + 128);
      float4 w3 = *(const float4*)(wr + 192);
      FMA4A(acc0, xv0)
      FMA4A(acc1, xv1)
      FMA4A(acc2, xv2)
      FMA4A(acc3, xv3)
    }
  }
  float4 acc[4] = {acc0, acc1, acc2, acc3};
  if (cbase < 32) {
    float4 bv = { bl[cbase], bl[cbase+1], bl[cbase+2], bl[cbase+3] };
#pragma unroll
    for (int j = 0; j < 4; ++j) {
      int n = n0 + j;
      if (n < NN) {
        uint2 o = { pack_bf2(acc[j].x + bv.x, acc[j].y + bv.y),
                    pack_bf2(acc[j].z + bv.z, acc[j].w + bv.w) };
        *(uint2*)(xl1b + (size_t)n * 32 + cbase) = o;
      }
    }
  } else {
    int c2 = cbase - 32;
    float4 bv = { br[c2], br[c2+1], br[c2+2], br[c2+3] };
#pragma unroll
    for (int j = 0; j < 4; ++j) {
      int n = n0 + j;
      if (n < NN) {
        float4 o = { acc[j].x + bv.x, acc[j].y + bv.y, acc[j].z + bv.z, acc[j].w + bv.w };
        *(float4*)(xr1 + (size_t)n * 32 + c2) = o;
      }
    }
  }
}

// ======================= merged kernels (role by blockIdx) =======================
__global__ __launch_bounds__(512) void k_part_x1(
    const int* __restrict__ ei, int* __restrict__ gcur, int* __restrict__ bedge,
    const float* __restrict__ x,
    const float* __restrict__ Wl, const float* __restrict__ bl,
    const float* __restrict__ Wr, const float* __restrict__ br,
    unsigned short* __restrict__ xl1b, float* __restrict__ xr1) {
  extern __shared__ char smem[];
  if (blockIdx.x < PBLOCKS)
    part_role(smem, ei, gcur, bedge, blockIdx.x);
  else
    xform1_role(smem, x, Wl, bl, Wr, br, xl1b, xr1, (blockIdx.x - PBLOCKS) * 128);
}

__global__ __launch_bounds__(512) void k_csr_x1(
    const int* __restrict__ boff, const int* __restrict__ bedge,
    int* __restrict__ rp, int* __restrict__ esrc,
    const float* __restrict__ x,
    const float* __restrict__ Wl, const float* __restrict__ bl,
    const float* __restrict__ Wr, const float* __restrict__ br,
    unsigned short* __restrict__ xl1b, float* __restrict__ xr1) {
  extern __shared__ char smem[];
  if (blockIdx.x < NB)
    csr_role(smem, boff, bedge, rp, esrc, blockIdx.x);
  else
    xform1_role(smem, x, Wl, bl, Wr, br, xl1b, xr1,
                X1_SPLIT + (blockIdx.x - NB) * 128);
}

// ======================= fused layer-1 gather + layer-2 transform + att-dot =====
// gather phase: 32 lanes/node, 8 nodes/block, unroll x4 -> h in LDS;
// xform phase: thread (ni,ci) computes node ni, cols ci*4..+3 of 128 from LDS W2;
// epilogue: AL2[n] = sum att2*hl2 (bf16-rounded), AR2[n] = sum att2*hr2.
__global__ __launch_bounds__(256) void k_gather1x2(
    const int* __restrict__ rp, const int* __restrict__ esrc,
    const unsigned short* __restrict__ xl1b, const float* __restrict__ xr1,
    const float* __restrict__ att1, const float* __restrict__ bias1,
    const float* __restrict__ W2l, const float* __restrict__ b2l,
    const float* __restrict__ W2r, const float* __restrict__ b2r,
    const float* __restrict__ att2,
    unsigned short* __restrict__ hl2b, float* __restrict__ hr2,
    float* __restrict__ AL2, float* __restrict__ AR2) {
  __shared__ float W2lds[32 * 128];   // 16 KB
  __shared__ float hlds[8][33];       // +1 pad
  int tid = threadIdx.x;
  for (int i = tid; i < 32 * 128; i += 256) {
    int k = i >> 7, c = i & 127;
    W2lds[i] = (c < 64) ? W2l[k * 64 + c] : W2r[k * 64 + (c - 64)];
  }
  int n = blockIdx.x * 8 + (tid >> 5);   // NN % 8 == 0, grid exact
  int l = tid & 31;
  float av = att1[l];
  float xr = xr1[(size_t)n * 32 + l];
  int rpn = rp[n], dg = rp[n + 1] - rpn;
  float acc = 0.0f, den = 0.0f;
  int j = 0;
  for (; j + 4 <= dg; j += 4) {
    int s0 = esrc[rpn + j + 0];
    int s1 = esrc[rpn + j + 1];
    int s2 = esrc[rpn + j + 2];
    int s3 = esrc[rpn + j + 3];
    float x0 = bf_lo(xl1b[(size_t)s0 * 32 + l]);
    float x1 = bf_lo(xl1b[(size_t)s1 * 32 + l]);
    float x2 = bf_lo(xl1b[(size_t)s2 * 32 + l]);
    float x3 = bf_lo(xl1b[(size_t)s3 * 32 + l]);
    float p0 = lrelu(x0 + xr) * av;
    float p1 = lrelu(x1 + xr) * av;
    float p2 = lrelu(x2 + xr) * av;
    float p3 = lrelu(x3 + xr) * av;
    p0 += __shfl_xor(p0, 1); p1 += __shfl_xor(p1, 1);
    p2 += __shfl_xor(p2, 1); p3 += __shfl_xor(p3, 1);
    p0 += __shfl_xor(p0, 2); p1 += __shfl_xor(p1, 2);
    p2 += __shfl_xor(p2, 2); p3 += __shfl_xor(p3, 2);
    float w0 = __expf(p0), w1 = __expf(p1), w2 = __expf(p2), w3 = __expf(p3);
    den += w0 + w1 + w2 + w3;
    acc += w0 * x0 + w1 * x1 + w2 * x2 + w3 * x3;
  }
  for (; j < dg; ++j) {
    int s = esrc[rpn + j];
    float xl = bf_lo(xl1b[(size_t)s * 32 + l]);
    float p = lrelu(xl + xr) * av;
    p += __shfl_xor(p, 1);
    p += __shfl_xor(p, 2);
    float w = __expf(p);
    den += w;
    acc += w * xl;
  }
  float v = acc / (den + 1e-16f) + bias1[l];
  v = v > 0.0f ? v : expm1f(v);
  hlds[tid >> 5][l] = v;
  __syncthreads();

  // layer-2 transform from LDS
  int ni = tid >> 5, ci = tid & 31, cbase = ci * 4;
  float4 a = {0,0,0,0};
#pragma unroll
  for (int k = 0; k < 32; ++k) {
    float hv = hlds[ni][k];
    float4 wv = *(const float4*)(&W2lds[k * 128 + cbase]);
    a.x += hv * wv.x; a.y += hv * wv.y; a.z += hv * wv.z; a.w += hv * wv.w;
  }
  int no = blockIdx.x * 8 + ni;
  float partial;
  if (cbase < 64) {
    uint2 o = { pack_bf2(a.x + b2l[cbase], a.y + b2l[cbase + 1]),
                pack_bf2(a.z + b2l[cbase + 2], a.w + b2l[cbase + 3]) };
    *(uint2*)(hl2b + (size_t)no * 64 + cbase) = o;
    // att-dot over the bf16-rounded values (matches what gather2 reads)
    partial = bf_lo(o.x) * att2[cbase + 0] + bf_hi(o.x) * att2[cbase + 1]
            + bf_lo(o.y) * att2[cbase + 2] + bf_hi(o.y) * att2[cbase + 3];
  } else {
    int c2 = cbase - 64;
    float4 o = { a.x + b2r[c2], a.y + b2r[c2 + 1], a.z + b2r[c2 + 2], a.w + b2r[c2 + 3] };
    *(float4*)(hr2 + (size_t)no * 64 + c2) = o;
    partial = o.x * att2[c2 + 0] + o.y * att2[c2 + 1]
            + o.z * att2[c2 + 2] + o.w * att2[c2 + 3];
  }
  // reduce within each 16-lane half (xor bits 0..3 stay inside the half)
  partial += __shfl_xor(partial, 1);
  partial += __shfl_xor(partial, 2);
  partial += __shfl_xor(partial, 4);
  partial += __shfl_xor(partial, 8);
  if (ci == 0)  AL2[no] = partial;
  if (ci == 16) AR2[no] = partial;
}

// ======================= layer-2 gather + pooling, unroll x4, abs-trick =========
// p = 0.6*(AL2[s]+AR2[d]) + 0.4*sum att*|hl+hr|   (lrelu(v)=0.6v+0.4|v|)
#define G2_P(qq, pp) { \
  float4 U0 = { bf_lo(qq.x), bf_hi(qq.x), bf_lo(qq.y), bf_hi(qq.y) }; \
  float4 U1 = { bf_lo(qq.z), bf_hi(qq.z), bf_lo(qq.w), bf_hi(qq.w) }; \
  pp = fabsf(U0.x + hr0.x) * ac0.x + fabsf(U0.y + hr0.y) * ac0.y \
     + fabsf(U0.z + hr0.z) * ac0.z + fabsf(U0.w + hr0.w) * ac0.w \
     + fabsf(U1.x + hr1.x) * ac1.x + fabsf(U1.y + hr1.y) * ac1.y \
     + fabsf(U1.z + hr1.z) * ac1.z + fabsf(U1.w + hr1.w) * ac1.w; }

#define G2_ACC(qq, ww) { \
  float4 U0 = { bf_lo(qq.x), bf_hi(qq.x), bf_lo(qq.y), bf_hi(qq.y) }; \
  float4 U1 = { bf_lo(qq.z), bf_hi(qq.z), bf_lo(qq.w), bf_hi(qq.w) }; \
  a0.x += ww * U0.x; a0.y += ww * U0.y; a0.z += ww * U0.z; a0.w += ww * U0.w; \
  a1.x += ww * U1.x; a1.y += ww * U1.y; a1.z += ww * U1.z; a1.w += ww * U1.w; }

__global__ __launch_bounds__(256) void k_gather2(
    const int* __restrict__ rp, const int* __restrict__ esrc,
    const unsigned short* __restrict__ hl2b, const float* __restrict__ hr2,
    const float* __restrict__ att2, const float* __restrict__ bias2,
    const int* __restrict__ batch,
    const float* __restrict__ AL2, const float* __restrict__ AR2,
    float* __restrict__ pool, float* __restrict__ cntg) {
  __shared__ float ssum[4][64];
  __shared__ float scnt[4];
  int tid = threadIdx.x;
  int n = (blockIdx.x * 256 + tid) >> 3;
  int l8 = tid & 7;
  int nblk0 = blockIdx.x * 32;
  int gmin = batch[nblk0];
  int gspan = batch[nblk0 + 31] - gmin + 1;   // <=4 (min graph size >> 32)
  ssum[tid >> 6][tid & 63] = 0.0f;
  if (tid < 4) scnt[tid] = 0.0f;
  __syncthreads();

  float4 ac0 = *(const float4*)(att2 + l8 * 8);
  float4 ac1 = *(const float4*)(att2 + l8 * 8 + 4);
  float4 bs0 = *(const float4*)(bias2 + l8 * 8);
  float4 bs1 = *(const float4*)(bias2 + l8 * 8 + 4);
  const float4* hrp = (const float4*)(hr2 + (size_t)n * 64 + l8 * 8);
  float4 hr0 = hrp[0], hr1 = hrp[1];
  float ard = 0.6f * AR2[n];
  int rpn = rp[n], dg = rp[n + 1] - rpn;
  float4 a0 = {0,0,0,0}, a1 = {0,0,0,0};
  float den = 0.0f;
  int j = 0;
  for (; j + 4 <= dg; j += 4) {
    int s0 = esrc[rpn + j + 0];
    int s1 = esrc[rpn + j + 1];
    int s2 = esrc[rpn + j + 2];
    int s3 = esrc[rpn + j + 3];
    uint4 q0 = *(const uint4*)(hl2b + (size_t)s0 * 64 + l8 * 8);
    uint4 q1 = *(const uint4*)(hl2b + (size_t)s1 * 64 + l8 * 8);
    uint4 q2 = *(const uint4*)(hl2b + (size_t)s2 * 64 + l8 * 8);
    uint4 q3 = *(const uint4*)(hl2b + (size_t)s3 * 64 + l8 * 8);
    float al0 = AL2[s0], al1 = AL2[s1], al2 = AL2[s2], al3 = AL2[s3];
    float p0, p1, p2, p3;
    G2_P(q0, p0) G2_P(q1, p1) G2_P(q2, p2) G2_P(q3, p3)
    p0 += __shfl_xor(p0, 1); p1 += __shfl_xor(p1, 1);
    p2 += __shfl_xor(p2, 1); p3 += __shfl_xor(p3, 1);
    p0 += __shfl_xor(p0, 2); p1 += __shfl_xor(p1, 2);
    p2 += __shfl_xor(p2, 2); p3 += __shfl_xor(p3, 2);
    p0 += __shfl_xor(p0, 4); p1 += __shfl_xor(p1, 4);
    p2 += __shfl_xor(p2, 4); p3 += __shfl_xor(p3, 4);
    float w0 = __expf(fmaf(0.6f, al0, fmaf(0.4f, p0, ard)));
    float w1 = __expf(fmaf(0.6f, al1, fmaf(0.4f, p1, ard)));
    float w2 = __expf(fmaf(0.6f, al2, fmaf(0.4f, p2, ard)));
    float w3 = __expf(fmaf(0.6f, al3, fmaf(0.4f, p3, ard)));
    den += w0 + w1 + w2 + w3;
    G2_ACC(q0, w0) G2_ACC(q1, w1) G2_ACC(q2, w2) G2_ACC(q3, w3)
  }
  for (; j < dg; ++j) {
    int s = esrc[rpn + j];
    uint4 q0 = *(const uint4*)(hl2b + (size_t)s * 64 + l8 * 8);
    float al = AL2[s];
    float p;
    G2_P(q0, p)
    p += __shfl_xor(p, 1);
    p += __shfl_xor(p, 2);
    p += __shfl_xor(p, 4);
    float w = __expf(fmaf(0.6f, al, fmaf(0.4f, p, ard)));
    den += w;
    G2_ACC(q0, w)
  }
  float inv = 1.0f / (den + 1e-16f);
  int gi = batch[n] - gmin;
  float* sp = &ssum[gi][l8 * 8];
  atomicAdd(sp + 0, a0.x * inv + bs0.x);
  atomicAdd(sp + 1, a0.y * inv + bs0.y);
  atomicAdd(sp + 2, a0.z * inv + bs0.z);
  atomicAdd(sp + 3, a0.w * inv + bs0.w);
  atomicAdd(sp + 4, a1.x * inv + bs1.x);
  atomicAdd(sp + 5, a1.y * inv + bs1.y);
  atomicAdd(sp + 6, a1.z * inv + bs1.z);
  atomicAdd(sp + 7, a1.w * inv + bs1.w);
  if (l8 == 0) atomicAdd(&scnt[gi], 1.0f);
  __syncthreads();
  for (int i = tid; i < gspan * 64; i += 256)
    atomicAdd(pool + (size_t)(gmin + (i >> 6)) * 64 + (i & 63), ssum[i >> 6][i & 63]);
  if (tid < gspan) atomicAdd(cntg + gmin + tid, scnt[tid]);
}

__global__ __launch_bounds__(256) void k_final(
    const float* __restrict__ pool, const float* __restrict__ cntg,
    float* __restrict__ out) {
  int i = blockIdx.x * 256 + threadIdx.x;
  if (i < NG * 64) out[i] = pool[i] / fmaxf(cntg[i >> 6], 1.0f);
}

extern "C" void kernel_launch(void* const* d_in, const int* in_sizes, int n_in,
                              void* d_out, int out_size, void* d_ws, size_t ws_size,
                              hipStream_t stream) {
  const float* x     = (const float*)d_in[0];
  const int*   ei    = (const int*)d_in[1];
  const int*   batch = (const int*)d_in[2];
  const float* W1l   = (const float*)d_in[3];
  const float* b1l   = (const float*)d_in[4];
  const float* W1r   = (const float*)d_in[5];
  const float* b1r   = (const float*)d_in[6];
  const float* att1  = (const float*)d_in[7];
  const float* bias1 = (const float*)d_in[8];
  const float* W2l   = (const float*)d_in[9];
  const float* b2l   = (const float*)d_in[10];
  const float* W2r   = (const float*)d_in[11];
  const float* b2r   = (const float*)d_in[12];
  const float* att2  = (const float*)d_in[13];
  const float* bias2 = (const float*)d_in[14];
  float* ws = (float*)d_ws;
  int*   wi = (int*)d_ws;
  float* out = (float*)d_out;

  // zero pool + cntg + bcnt (contiguous region)
  hipMemsetAsync(ws + OFF_POOL, 0, (size_t)(OFF_AL2 - OFF_POOL) * 4, stream);

  // CSR build; xform1 halves ride along in the part/csr launches (independent work)
  k_bcount<<<512, 256, 0, stream>>>(ei, wi + OFF_BCNT);
  k_bscan<<<1, 256, 0, stream>>>(wi + OFF_BCNT, wi + OFF_BOFF, wi + OFF_GCUR);
  k_part_x1<<<PBLOCKS + X1BLK_A, 512, 44352, stream>>>(
      ei, wi + OFF_GCUR, wi + OFF_BEDGE,
      x, W1l, b1l, W1r, b1r, (unsigned short*)(ws + OFF_XL1B), ws + OFF_XR1);
  k_csr_x1<<<NB + X1BLK_B, 512, 16384, stream>>>(
      wi + OFF_BOFF, wi + OFF_BEDGE, wi + OFF_RP, wi + OFF_ESRC,
      x, W1l, b1l, W1r, b1r, (unsigned short*)(ws + OFF_XL1B), ws + OFF_XR1);

  // fused layer-1 gather + layer-2 transform + att-dot precompute
  k_gather1x2<<<NN / 8, 256, 0, stream>>>(wi + OFF_RP, wi + OFF_ESRC,
                                          (const unsigned short*)(ws + OFF_XL1B), ws + OFF_XR1,
                                          att1, bias1, W2l, b2l, W2r, b2r, att2,
                                          (unsigned short*)(ws + OFF_HL2B), ws + OFF_HR2,
                                          ws + OFF_AL2, ws + OFF_AR2);
  k_gather2<<<(NN * 8 + 255) / 256, 256, 0, stream>>>(wi + OFF_RP, wi + OFF_ESRC,
                                                      (const unsigned short*)(ws + OFF_HL2B),
                                                      ws + OFF_HR2, att2, bias2, batch,
                                                      ws + OFF_AL2, ws + OFF_AR2,
                                                      ws + OFF_POOL, ws + OFF_CNTG);
  k_final<<<16, 256, 0, stream>>>(ws + OFF_POOL, ws + OFF_CNTG, out);
}